// Round 1
// 10400.025 us; speedup vs baseline: 1.3014x; 1.3014x over previous
//
#include <hip/hip_runtime.h>
#include <hip/hip_fp16.h>
#include <math.h>

// Problem dims
#define T_STEPS 1024
#define BATCH   128
#define D_IN    256
#define H_DIM   256
#define NCOL    1024  // 4 gates * H

typedef _Float16 half2_t __attribute__((ext_vector_type(2)));

__device__ __forceinline__ float sigmoidf_(float x) {
    return 1.0f / (1.0f + __expf(-x));
}

__device__ __forceinline__ float tanhf_(float x) {
    float ax = fabsf(x);
    float t = __expf(-2.0f * ax);
    float r = (1.0f - t) / (1.0f + t);
    return copysignf(r, x);
}

// 2-way f16 dot with f32 accumulate: acc += w.x*h.x + w.y*h.y
__device__ __forceinline__ float dot2f(unsigned int w, unsigned int h, float acc) {
#if __has_builtin(__builtin_amdgcn_fdot2)
    return __builtin_amdgcn_fdot2(__builtin_bit_cast(half2_t, w),
                                  __builtin_bit_cast(half2_t, h), acc, false);
#else
    __half2 wv = *(__half2*)&w, hv = *(__half2*)&h;
    acc = fmaf(__half2float(wv.x), __half2float(hv.x), acc);
    return fmaf(__half2float(wv.y), __half2float(hv.y), acc);
#endif
}

__device__ __forceinline__ unsigned int packh2(float a, float b) {
    __half2 p = __floats2half2_rn(a, b);
    return *(unsigned int*)&p;
}

// Layouts:
//   WX2[k2*1024 + j]  = half2(W[h][2k2], W[h][2k2+1])       (legacy, for pregemm)
//   WX4[m*1024 + j]   = uint4 packing half(W[h][8m..8m+7])   (x part, col-major octets)
//   WH4[m*1024 + j]   = uint4 packing half(W[h][256+8m..+7]) (hx part)
// with j = gate*256 + h, m = 0..31.  Plus combined bias biasc[1024] (fp32).
__global__ __launch_bounds__(256) void prep_kernel(
    const float* __restrict__ Wf, const float* __restrict__ Wi,
    const float* __restrict__ Wg, const float* __restrict__ Wo,
    const float* __restrict__ bf, const float* __restrict__ bi,
    const float* __restrict__ bg, const float* __restrict__ bo,
    unsigned int* __restrict__ WX2, uint4* __restrict__ WX4,
    uint4* __restrict__ WH4, float* __restrict__ biasc)
{
    int idx = blockIdx.x * 256 + threadIdx.x;   // 0 .. 32*1024-1
    int m = idx >> 10;
    int j = idx & 1023;
    int g = j >> 8;
    int h = j & 255;
    const float* W = (g == 0) ? Wf : (g == 1) ? Wi : (g == 2) ? Wg : Wo;
    const float* row = W + h * (D_IN + H_DIM);
    const float* rx = row + 8 * m;
    const float* rh = row + D_IN + 8 * m;
    uint4 vx = make_uint4(packh2(rx[0], rx[1]), packh2(rx[2], rx[3]),
                          packh2(rx[4], rx[5]), packh2(rx[6], rx[7]));
    uint4 vh = make_uint4(packh2(rh[0], rh[1]), packh2(rh[2], rh[3]),
                          packh2(rh[4], rh[5]), packh2(rh[6], rh[7]));
    WX4[idx] = vx;
    WH4[idx] = vh;
    // legacy [k2][j] layout for pregemm
    unsigned int* d = (unsigned int*)&vx;
    #pragma unroll
    for (int p = 0; p < 4; p++) WX2[(4 * m + p) * 1024 + j] = d[p];
    if (idx < NCOL) {
        const float* bb = (g == 0) ? bf : (g == 1) ? bi : (g == 2) ? bg : bo;
        biasc[j] = bb[h];
    }
}

// pre[r][j] = bias[j] + sum_d x[r][d]*Wx[j][d], r = t*B+b (fully parallel GEMM)
// One WG per 16 rows; thread tid owns cols 4*tid..4*tid+3.
__global__ __launch_bounds__(256) void pregemm_kernel(
    const float* __restrict__ x, const unsigned int* __restrict__ WX2,
    const float* __restrict__ biasc, float* __restrict__ pre) {
    __shared__ float xs[16 * 256];   // 16 KB x tile
    const int tid = threadIdx.x;
    const size_t r0 = (size_t)blockIdx.x * 16;

    {
        const float4* xsrc = (const float4*)(x + r0 * D_IN);
        float4* xd = (float4*)xs;
        #pragma unroll
        for (int i = 0; i < 4; i++) xd[tid + 256 * i] = xsrc[tid + 256 * i];
    }
    float4 b4 = ((const float4*)biasc)[tid];
    float a[16][4];
    #pragma unroll
    for (int r = 0; r < 16; r++) {
        a[r][0] = b4.x; a[r][1] = b4.y; a[r][2] = b4.z; a[r][3] = b4.w;
    }
    __syncthreads();

    const uint4* wp = (const uint4*)WX2;
    const float2* xs2 = (const float2*)xs;
    #pragma unroll 2
    for (int k2 = 0; k2 < 128; k2++) {
        uint4 wv = wp[k2 * 256 + tid];
        __half2 q0 = *(__half2*)&wv.x, q1 = *(__half2*)&wv.y;
        __half2 q2 = *(__half2*)&wv.z, q3 = *(__half2*)&wv.w;
        float w0l = __half2float(q0.x), w0h = __half2float(q0.y);
        float w1l = __half2float(q1.x), w1h = __half2float(q1.y);
        float w2l = __half2float(q2.x), w2h = __half2float(q2.y);
        float w3l = __half2float(q3.x), w3h = __half2float(q3.y);
        #pragma unroll
        for (int r = 0; r < 16; r++) {
            float2 xv = xs2[r * 128 + k2];
            a[r][0] = fmaf(xv.x, w0l, a[r][0]); a[r][0] = fmaf(xv.y, w0h, a[r][0]);
            a[r][1] = fmaf(xv.x, w1l, a[r][1]); a[r][1] = fmaf(xv.y, w1h, a[r][1]);
            a[r][2] = fmaf(xv.x, w2l, a[r][2]); a[r][2] = fmaf(xv.y, w2h, a[r][2]);
            a[r][3] = fmaf(xv.x, w3l, a[r][3]); a[r][3] = fmaf(xv.y, w3h, a[r][3]);
        }
    }
    #pragma unroll
    for (int r = 0; r < 16; r++) {
        ((float4*)(pre + (r0 + r) * NCOL))[tid] =
            make_float4(a[r][0], a[r][1], a[r][2], a[r][3]);
    }
}

// One WG per batch row; 1024 threads (16 waves -> 4 waves/SIMD for latency hiding).
// Thread tid owns gate column j = tid (j = gate*256 + h).
// Recurrent MAC via v_dot2_f32_f16 with hi/lo-split hx (precision ~= fp32 hx * f16 W).
__global__ __launch_bounds__(1024) void qlstm_kernel(
    const float* __restrict__ x,
    const uint4* __restrict__ WX4,
    const uint4* __restrict__ WH4,
    const float* __restrict__ biasc,
    const float* __restrict__ pre, int use_pre,
    const float* __restrict__ estW1, const float* __restrict__ estb1,
    const float* __restrict__ estW2, const float* __restrict__ estb2,
    const float* __restrict__ estW3, const float* __restrict__ estb3,
    float* __restrict__ out)
{
    __shared__ __align__(16) __half hxh[H_DIM];   // hi(hx)
    __shared__ __align__(16) __half hxl[H_DIM];   // lo(hx)
    __shared__ __align__(16) __half cxh[D_IN];    // hi(x)  (fallback path)
    __shared__ __align__(16) __half cxl[D_IN];    // lo(x)
    __shared__ __align__(16) float gact[NCOL];    // activated gates (pre est-scale)
    __shared__ float w1[4][8][H_DIM];   // estW1, permuted: [.][.][q*64+l] = orig h=4l+q
    __shared__ float sb1[32];
    __shared__ float sW2[128];
    __shared__ float sb2[16];
    __shared__ float sW3[16];
    __shared__ float sb3[4];
    __shared__ float escale[4];

    const int b    = blockIdx.x;
    const int tid  = threadIdx.x;
    const int w    = tid >> 6;      // wave id; for tid<256 this is the gate
    const int lane = tid & 63;

    // stage est params; permute w1 so lane-l float4 reads of gact are stride-1
    for (int i = tid; i < 4 * 8 * H_DIM; i += 1024) {
        int p = i & 255;                 // permuted pos
        int base = i & ~255;
        int h = 4 * (p & 63) + (p >> 6); // original h
        ((float*)w1)[i] = estW1[base + h];
    }
    if (tid < 32)  sb1[tid] = estb1[tid];
    if (tid < 128) sW2[tid] = estW2[tid];
    if (tid < 16)  { sb2[tid] = estb2[tid]; sW3[tid] = estW3[tid]; }
    if (tid < 4)   sb3[tid] = estb3[tid];
    if (tid < H_DIM) {
        hxh[tid] = __float2half(0.0f);
        hxl[tid] = __float2half(0.0f);
    }
    float c_reg = 0.0f, h_reg = 0.0f;
    const float b_j = use_pre ? 0.0f : biasc[tid];
    __syncthreads();

    const uint4* hh = (const uint4*)hxh;   // 32 x (8 halves) covering k=8m..8m+7
    const uint4* hl = (const uint4*)hxl;
    const uint4* xh = (const uint4*)cxh;
    const uint4* xl = (const uint4*)cxl;

    const float* prep_ = pre + (size_t)b * NCOL + tid;
    float pnext = use_pre ? prep_[0] : 0.0f;   // prefetch t=0

    for (int t = 0; t < T_STEPS; t++) {
        float aH, aL = 0.0f;
        if (use_pre) {
            aH = pnext;
            if (t + 1 < T_STEPS)                        // prefetch next step (HBM)
                pnext = prep_[(size_t)(t + 1) * BATCH * NCOL];
        } else {
            aH = b_j;
            if (tid < D_IN) {
                float xv = x[((size_t)t * BATCH + b) * D_IN + tid];
                __half hi = __float2half_rn(xv);
                cxh[tid] = hi;
                cxl[tid] = __float2half_rn(xv - __half2float(hi));
            }
            __syncthreads();
            #pragma unroll 4
            for (int m = 0; m < 32; m++) {
                uint4 wv = WX4[(m << 10) + tid];
                uint4 hv = xh[m], lv = xl[m];
                aH = dot2f(wv.x, hv.x, aH); aH = dot2f(wv.y, hv.y, aH);
                aH = dot2f(wv.z, hv.z, aH); aH = dot2f(wv.w, hv.w, aH);
                aL = dot2f(wv.x, lv.x, aL); aL = dot2f(wv.y, lv.y, aL);
                aL = dot2f(wv.z, lv.z, aL); aL = dot2f(wv.w, lv.w, aL);
            }
        }

        // recurrent part: col j = tid, k = 0..255 over hx
        #pragma unroll 4
        for (int m = 0; m < 32; m++) {
            uint4 wv = WH4[(m << 10) + tid];
            uint4 hv = hh[m], lv = hl[m];
            aH = dot2f(wv.x, hv.x, aH); aH = dot2f(wv.y, hv.y, aH);
            aH = dot2f(wv.z, hv.z, aH); aH = dot2f(wv.w, hv.w, aH);
            aL = dot2f(wv.x, lv.x, aL); aL = dot2f(wv.y, lv.y, aL);
            aL = dot2f(wv.z, lv.z, aL); aL = dot2f(wv.w, lv.w, aL);
        }
        float acc = aH + aL;

        // activation: gate 2 (tid 512..767) uses tanh, others sigmoid
        float v = (tid >= 512 && tid < 768) ? tanhf_(acc) : sigmoidf_(acc);
        gact[tid] = v;
        __syncthreads();   // A: gates visible

        // est MLP for gate w: waves 0..3 (one gate each), H->8 (wave-reduced) ->4 ->1
        if (tid < 256) {
            float4 gv = ((const float4*)(gact + (w << 8)))[lane];  // h = 4l..4l+3
            float h1[8];
            #pragma unroll
            for (int j = 0; j < 8; j++) {
                const float* wr = &w1[w][j][0];   // permuted layout
                float s = fmaf(gv.x, wr[lane],
                          fmaf(gv.y, wr[lane + 64],
                          fmaf(gv.z, wr[lane + 128], gv.w * wr[lane + 192])));
                #pragma unroll
                for (int m2 = 1; m2 < 64; m2 <<= 1) s += __shfl_xor(s, m2, 64);
                h1[j] = tanhf_(s + sb1[w * 8 + j]);
            }
            float h2[4];
            #pragma unroll
            for (int j = 0; j < 4; j++) {
                float s = sb2[w * 4 + j];
                #pragma unroll
                for (int q = 0; q < 8; q++) s = fmaf(h1[q], sW2[w * 32 + j * 8 + q], s);
                h2[j] = tanhf_(s);
            }
            float s3 = sb3[w];
            #pragma unroll
            for (int q = 0; q < 4; q++) s3 = fmaf(h2[q], sW3[w * 4 + q], s3);
            if (lane == 0) escale[w] = sigmoidf_(s3);
        }
        __syncthreads();   // B: escale visible

        // state update: thread tid < 256 owns h = tid
        if (tid < 256) {
            float f  = gact[tid]       * escale[0];
            float ii = gact[256 + tid] * escale[1];
            float gg = gact[512 + tid] * escale[2];
            float o  = gact[768 + tid] * escale[3];
            c_reg = fmaf(f, c_reg, ii * gg);
            h_reg = o * tanhf_(c_reg);
            __half hi = __float2half_rn(h_reg);
            hxh[tid] = hi;
            hxl[tid] = __float2half_rn(h_reg - __half2float(hi));
            out[((size_t)t * BATCH + b) * H_DIM + tid] = h_reg;
        }
        __syncthreads();   // C: new hx visible to all waves
    }

    if (tid < 256) {
        const size_t stacked = (size_t)T_STEPS * BATCH * H_DIM;
        out[stacked + (size_t)b * H_DIM + tid] = h_reg;
        out[stacked + (size_t)BATCH * H_DIM + (size_t)b * H_DIM + tid] = c_reg;
    }
}

extern "C" void kernel_launch(void* const* d_in, const int* in_sizes, int n_in,
                              void* d_out, int out_size, void* d_ws, size_t ws_size,
                              hipStream_t stream) {
    const float* x     = (const float*)d_in[0];
    const float* Wf    = (const float*)d_in[1];
    const float* bf    = (const float*)d_in[2];
    const float* Wi    = (const float*)d_in[3];
    const float* bi    = (const float*)d_in[4];
    const float* Wg    = (const float*)d_in[5];
    const float* bg    = (const float*)d_in[6];
    const float* Wo    = (const float*)d_in[7];
    const float* bo    = (const float*)d_in[8];
    const float* estW1 = (const float*)d_in[9];
    const float* estb1 = (const float*)d_in[10];
    const float* estW2 = (const float*)d_in[11];
    const float* estb2 = (const float*)d_in[12];
    const float* estW3 = (const float*)d_in[13];
    const float* estb3 = (const float*)d_in[14];

    unsigned int* WX2 = (unsigned int*)d_ws;           // 512 KB (legacy, pregemm)
    uint4* WX4   = (uint4*)(WX2 + 128 * 1024);         // 512 KB
    uint4* WH4   = WX4 + 32 * 1024;                    // 512 KB
    float* biasc = (float*)(WH4 + 32 * 1024);          // 4 KB
    float* pre   = biasc + NCOL;                       // [T*B][1024] fp32 = 512 MB

    const size_t need = (size_t)128 * 1024 * 4 * 3 + NCOL * 4 +
                        (size_t)T_STEPS * BATCH * NCOL * 4;
    const int use_pre = (ws_size >= need) ? 1 : 0;

    prep_kernel<<<128, 256, 0, stream>>>(Wf, Wi, Wg, Wo, bf, bi, bg, bo,
                                         WX2, WX4, WH4, biasc);
    if (use_pre) {
        pregemm_kernel<<<(T_STEPS * BATCH) / 16, 256, 0, stream>>>(x, WX2, biasc, pre);
    }
    qlstm_kernel<<<BATCH, 1024, 0, stream>>>(x, WX4, WH4, biasc, pre, use_pre,
                                             estW1, estb1, estW2, estb2, estW3, estb3,
                                             (float*)d_out);
}

// Round 2
// 10245.148 us; speedup vs baseline: 1.3210x; 1.0151x over previous
//
#include <hip/hip_runtime.h>
#include <hip/hip_fp16.h>
#include <math.h>

// Problem dims
#define T_STEPS 1024
#define BATCH   128
#define D_IN    256
#define H_DIM   256
#define NCOL    1024  // 4 gates * H

typedef _Float16 half2_t __attribute__((ext_vector_type(2)));

__device__ __forceinline__ float sigmoidf_(float x) {
    return 1.0f / (1.0f + __expf(-x));
}

__device__ __forceinline__ float tanhf_(float x) {
    float ax = fabsf(x);
    float t = __expf(-2.0f * ax);
    float r = (1.0f - t) / (1.0f + t);
    return copysignf(r, x);
}

// 2-way f16 dot with f32 accumulate: acc += w.x*h.x + w.y*h.y
__device__ __forceinline__ float dot2f(unsigned int w, unsigned int h, float acc) {
#if __has_builtin(__builtin_amdgcn_fdot2)
    return __builtin_amdgcn_fdot2(__builtin_bit_cast(half2_t, w),
                                  __builtin_bit_cast(half2_t, h), acc, false);
#else
    __half2 wv = *(__half2*)&w, hv = *(__half2*)&h;
    acc = fmaf(__half2float(wv.x), __half2float(hv.x), acc);
    return fmaf(__half2float(wv.y), __half2float(hv.y), acc);
#endif
}

__device__ __forceinline__ unsigned int packh2(float a, float b) {
    __half2 p = __floats2half2_rn(a, b);
    return *(unsigned int*)&p;
}

// pack value as (hi, lo-residual) f16 pair in one dword
__device__ __forceinline__ unsigned int packhl(float v) {
    __half hi = __float2half_rn(v);
    __half lo = __float2half_rn(v - __half2float(hi));
    __half2 p; p.x = hi; p.y = lo;
    return *(unsigned int*)&p;
}

// Layouts:
//   WX2[k2*1024 + j]  = half2(W[h][2k2], W[h][2k2+1])       (legacy, for pregemm)
//   WX4[m*1024 + j]   = uint4 packing half(W[h][8m..8m+7])   (x part, col-major octets)
//   WH4[m*1024 + j]   = uint4 packing half(W[h][256+8m..+7]) (hx part)
// with j = gate*256 + h, m = 0..31.  Plus combined bias biasc[1024] (fp32).
// Also zeroes the pair-sync flags (device-coherent stores).
__global__ __launch_bounds__(256) void prep_kernel(
    const float* __restrict__ Wf, const float* __restrict__ Wi,
    const float* __restrict__ Wg, const float* __restrict__ Wo,
    const float* __restrict__ bf, const float* __restrict__ bi,
    const float* __restrict__ bg, const float* __restrict__ bo,
    unsigned int* __restrict__ WX2, uint4* __restrict__ WX4,
    uint4* __restrict__ WH4, float* __restrict__ biasc,
    int* __restrict__ flags)
{
    int idx = blockIdx.x * 256 + threadIdx.x;   // 0 .. 32*1024-1
    if (idx < 8192) {
        __hip_atomic_store(&flags[idx], 0, __ATOMIC_RELAXED, __HIP_MEMORY_SCOPE_AGENT);
    }
    int m = idx >> 10;
    int j = idx & 1023;
    int g = j >> 8;
    int h = j & 255;
    const float* W = (g == 0) ? Wf : (g == 1) ? Wi : (g == 2) ? Wg : Wo;
    const float* row = W + h * (D_IN + H_DIM);
    const float* rx = row + 8 * m;
    const float* rh = row + D_IN + 8 * m;
    uint4 vx = make_uint4(packh2(rx[0], rx[1]), packh2(rx[2], rx[3]),
                          packh2(rx[4], rx[5]), packh2(rx[6], rx[7]));
    uint4 vh = make_uint4(packh2(rh[0], rh[1]), packh2(rh[2], rh[3]),
                          packh2(rh[4], rh[5]), packh2(rh[6], rh[7]));
    WX4[idx] = vx;
    WH4[idx] = vh;
    // legacy [k2][j] layout for pregemm
    unsigned int* d = (unsigned int*)&vx;
    #pragma unroll
    for (int p = 0; p < 4; p++) WX2[(4 * m + p) * 1024 + j] = d[p];
    if (idx < NCOL) {
        const float* bb = (g == 0) ? bf : (g == 1) ? bi : (g == 2) ? bg : bo;
        biasc[j] = bb[h];
    }
}

// pre[r][j] = bias[j] + sum_d x[r][d]*Wx[j][d], r = t*B+b (fully parallel GEMM)
__global__ __launch_bounds__(256) void pregemm_kernel(
    const float* __restrict__ x, const unsigned int* __restrict__ WX2,
    const float* __restrict__ biasc, float* __restrict__ pre) {
    __shared__ float xs[16 * 256];   // 16 KB x tile
    const int tid = threadIdx.x;
    const size_t r0 = (size_t)blockIdx.x * 16;

    {
        const float4* xsrc = (const float4*)(x + r0 * D_IN);
        float4* xd = (float4*)xs;
        #pragma unroll
        for (int i = 0; i < 4; i++) xd[tid + 256 * i] = xsrc[tid + 256 * i];
    }
    float4 b4 = ((const float4*)biasc)[tid];
    float a[16][4];
    #pragma unroll
    for (int r = 0; r < 16; r++) {
        a[r][0] = b4.x; a[r][1] = b4.y; a[r][2] = b4.z; a[r][3] = b4.w;
    }
    __syncthreads();

    const uint4* wp = (const uint4*)WX2;
    const float2* xs2 = (const float2*)xs;
    #pragma unroll 2
    for (int k2 = 0; k2 < 128; k2++) {
        uint4 wv = wp[k2 * 256 + tid];
        __half2 q0 = *(__half2*)&wv.x, q1 = *(__half2*)&wv.y;
        __half2 q2 = *(__half2*)&wv.z, q3 = *(__half2*)&wv.w;
        float w0l = __half2float(q0.x), w0h = __half2float(q0.y);
        float w1l = __half2float(q1.x), w1h = __half2float(q1.y);
        float w2l = __half2float(q2.x), w2h = __half2float(q2.y);
        float w3l = __half2float(q3.x), w3h = __half2float(q3.y);
        #pragma unroll
        for (int r = 0; r < 16; r++) {
            float2 xv = xs2[r * 128 + k2];
            a[r][0] = fmaf(xv.x, w0l, a[r][0]); a[r][0] = fmaf(xv.y, w0h, a[r][0]);
            a[r][1] = fmaf(xv.x, w1l, a[r][1]); a[r][1] = fmaf(xv.y, w1h, a[r][1]);
            a[r][2] = fmaf(xv.x, w2l, a[r][2]); a[r][2] = fmaf(xv.y, w2h, a[r][2]);
            a[r][3] = fmaf(xv.x, w3l, a[r][3]); a[r][3] = fmaf(xv.y, w3h, a[r][3]);
        }
    }
    #pragma unroll
    for (int r = 0; r < 16; r++) {
        ((float4*)(pre + (r0 + r) * NCOL))[tid] =
            make_float4(a[r][0], a[r][1], a[r][2], a[r][3]);
    }
}

// ---------------------------------------------------------------------------
// Pair kernel: 256 blocks; pair (A=2b, B=2b+1) owns batch row b.
// A: recurrent partial over h[0..127].  B: h[128..255] + pre + est + update.
// Comm (partial 4KB, h-low 512B, flags) via agent-scope cache-bypassing atomics
// through the LLC (no cross-XCD L2 coherence assumed).
// 48KB LDS pad forces 1 block/CU -> all 256 blocks co-resident -> spins safe.
// ---------------------------------------------------------------------------
__global__ __launch_bounds__(1024) void qlstm_pair_kernel(
    const uint4* __restrict__ WH4,
    const float* __restrict__ pre,
    float* __restrict__ partial,
    unsigned int* __restrict__ hxbuf,
    int* __restrict__ flags,
    const float* __restrict__ estW1, const float* __restrict__ estb1,
    const float* __restrict__ estW2, const float* __restrict__ estb2,
    const float* __restrict__ estW3, const float* __restrict__ estb3,
    float* __restrict__ out)
{
    __shared__ __align__(16) __half hxh[128];   // hi of local k-half of h
    __shared__ __align__(16) __half hxl[128];   // lo
    __shared__ __align__(16) float gact[NCOL];  // activated gates (B only)
    __shared__ float w1[4][8][H_DIM];
    __shared__ float sb1[32];
    __shared__ float sW2[128];
    __shared__ float sb2[16];
    __shared__ float sW3[16];
    __shared__ float sb3[4];
    __shared__ float escale[4];
    __shared__ float xpad[12288];               // 48 KB: forces 1 block/CU

    const int b    = blockIdx.x >> 1;
    const int role = blockIdx.x & 1;            // 0 = A (k-low), 1 = B (finisher)
    const int tid  = threadIdx.x;

    // keep the pad alive without ever touching it
    if (blockIdx.x == 0x7FFFFFFF) ((volatile float*)xpad)[tid] = 1.0f;

    int* flagA = flags + b * 32;
    int* flagB = flags + 4096 + b * 32;
    float* part_p = partial + (size_t)b * NCOL + tid;
    unsigned int* hx_p = hxbuf + (size_t)b * 128;

    if (tid < 128) { hxh[tid] = __float2half(0.0f); hxl[tid] = __float2half(0.0f); }

    const uint4* hh = (const uint4*)hxh;   // 16 x (8 halves)
    const uint4* hl = (const uint4*)hxl;

    if (role == 0) {
        // ------------------------------ A ------------------------------
        __syncthreads();
        const uint4* Wlo = WH4;            // m = 0..15 -> k = 0..127 of h
        for (int t = 0; t < T_STEPS; t++) {
            float aH = 0.0f, aL = 0.0f;
            #pragma unroll
            for (int m = 0; m < 16; m++) {
                uint4 wv = Wlo[(m << 10) + tid];
                uint4 hv = hh[m], lv = hl[m];
                aH = dot2f(wv.x, hv.x, aH); aH = dot2f(wv.y, hv.y, aH);
                aH = dot2f(wv.z, hv.z, aH); aH = dot2f(wv.w, hv.w, aH);
                aL = dot2f(wv.x, lv.x, aL); aL = dot2f(wv.y, lv.y, aL);
                aL = dot2f(wv.z, lv.z, aL); aL = dot2f(wv.w, lv.w, aL);
            }
            __hip_atomic_store(part_p, aH + aL, __ATOMIC_RELAXED, __HIP_MEMORY_SCOPE_AGENT);
            __syncthreads();   // all partial stores drained (vmcnt 0) before flag
            if (tid == 0)
                __hip_atomic_store(flagA, t + 1, __ATOMIC_RELEASE, __HIP_MEMORY_SCOPE_AGENT);
            if (t + 1 < T_STEPS) {
                if (tid == 0) {
                    while (__hip_atomic_load(flagB, __ATOMIC_ACQUIRE,
                                             __HIP_MEMORY_SCOPE_AGENT) < t + 1)
                        __builtin_amdgcn_s_sleep(1);
                }
                __syncthreads();
                if (tid < 128) {
                    unsigned int u = __hip_atomic_load(&hx_p[tid], __ATOMIC_RELAXED,
                                                       __HIP_MEMORY_SCOPE_AGENT);
                    __half2 p = *(__half2*)&u;
                    hxh[tid] = p.x; hxl[tid] = p.y;
                }
                __syncthreads();
            }
        }
        return;
    }

    // ------------------------------ B ------------------------------
    const int w    = tid >> 6;
    const int lane = tid & 63;

    for (int i = tid; i < 4 * 8 * H_DIM; i += 1024) {
        int p = i & 255;
        int base = i & ~255;
        int h = 4 * (p & 63) + (p >> 6);
        ((float*)w1)[i] = estW1[base + h];
    }
    if (tid < 32)  sb1[tid] = estb1[tid];
    if (tid < 128) sW2[tid] = estW2[tid];
    if (tid < 16)  { sb2[tid] = estb2[tid]; sW3[tid] = estW3[tid]; }
    if (tid < 4)   sb3[tid] = estb3[tid];
    float c_reg = 0.0f, h_reg = 0.0f;
    __syncthreads();

    const uint4* Whi = WH4 + (16 << 10);   // m = 16..31 -> k = 128..255 of h
    const float* prep_ = pre + (size_t)b * NCOL + tid;
    float pnext = prep_[0];

    for (int t = 0; t < T_STEPS; t++) {
        float aH = pnext, aL = 0.0f;
        if (t + 1 < T_STEPS)
            pnext = prep_[(size_t)(t + 1) * BATCH * NCOL];   // HBM prefetch, 1 step ahead
        #pragma unroll
        for (int m = 0; m < 16; m++) {
            uint4 wv = Whi[(m << 10) + tid];
            uint4 hv = hh[m], lv = hl[m];
            aH = dot2f(wv.x, hv.x, aH); aH = dot2f(wv.y, hv.y, aH);
            aH = dot2f(wv.z, hv.z, aH); aH = dot2f(wv.w, hv.w, aH);
            aL = dot2f(wv.x, lv.x, aL); aL = dot2f(wv.y, lv.y, aL);
            aL = dot2f(wv.z, lv.z, aL); aL = dot2f(wv.w, lv.w, aL);
        }
        if (tid == 0) {
            while (__hip_atomic_load(flagA, __ATOMIC_ACQUIRE,
                                     __HIP_MEMORY_SCOPE_AGENT) < t + 1)
                __builtin_amdgcn_s_sleep(1);
        }
        __syncthreads();
        float pA = __hip_atomic_load(part_p, __ATOMIC_RELAXED, __HIP_MEMORY_SCOPE_AGENT);
        float acc = aH + aL + pA;

        float v = (tid >= 512 && tid < 768) ? tanhf_(acc) : sigmoidf_(acc);
        gact[tid] = v;
        __syncthreads();   // gates visible

        if (tid < 256) {
            float4 gv = ((const float4*)(gact + (w << 8)))[lane];
            float h1[8];
            #pragma unroll
            for (int j = 0; j < 8; j++) {
                const float* wr = &w1[w][j][0];
                float s = fmaf(gv.x, wr[lane],
                          fmaf(gv.y, wr[lane + 64],
                          fmaf(gv.z, wr[lane + 128], gv.w * wr[lane + 192])));
                #pragma unroll
                for (int m2 = 1; m2 < 64; m2 <<= 1) s += __shfl_xor(s, m2, 64);
                h1[j] = tanhf_(s + sb1[w * 8 + j]);
            }
            float h2[4];
            #pragma unroll
            for (int j = 0; j < 4; j++) {
                float s = sb2[w * 4 + j];
                #pragma unroll
                for (int q = 0; q < 8; q++) s = fmaf(h1[q], sW2[w * 32 + j * 8 + q], s);
                h2[j] = tanhf_(s);
            }
            float s3 = sb3[w];
            #pragma unroll
            for (int q = 0; q < 4; q++) s3 = fmaf(h2[q], sW3[w * 4 + q], s3);
            if (lane == 0) escale[w] = sigmoidf_(s3);
        }
        __syncthreads();   // escale visible

        if (tid < 256) {
            float f  = gact[tid]       * escale[0];
            float ii = gact[256 + tid] * escale[1];
            float gg = gact[512 + tid] * escale[2];
            float o  = gact[768 + tid] * escale[3];
            c_reg = fmaf(f, c_reg, ii * gg);
            h_reg = o * tanhf_(c_reg);
            out[((size_t)t * BATCH + b) * H_DIM + tid] = h_reg;
            unsigned int u = packhl(h_reg);
            if (tid < 128) {
                __hip_atomic_store(&hx_p[tid], u, __ATOMIC_RELAXED, __HIP_MEMORY_SCOPE_AGENT);
            } else {
                __half2 p = *(__half2*)&u;
                hxh[tid - 128] = p.x; hxl[tid - 128] = p.y;
            }
        }
        __syncthreads();   // hxbuf drained + local h staged
        if (tid == 0)
            __hip_atomic_store(flagB, t + 1, __ATOMIC_RELEASE, __HIP_MEMORY_SCOPE_AGENT);
    }

    if (tid < 256) {
        const size_t stacked = (size_t)T_STEPS * BATCH * H_DIM;
        out[stacked + (size_t)b * H_DIM + tid] = h_reg;
        out[stacked + (size_t)BATCH * H_DIM + (size_t)b * H_DIM + tid] = c_reg;
    }
}

// ---------------------------------------------------------------------------
// Fallback (small workspace): round-1 single-block-per-row kernel, full k,
// x-GEMV computed on the fly.
// ---------------------------------------------------------------------------
__global__ __launch_bounds__(1024) void qlstm_fallback_kernel(
    const float* __restrict__ x,
    const uint4* __restrict__ WX4,
    const uint4* __restrict__ WH4,
    const float* __restrict__ biasc,
    const float* __restrict__ estW1, const float* __restrict__ estb1,
    const float* __restrict__ estW2, const float* __restrict__ estb2,
    const float* __restrict__ estW3, const float* __restrict__ estb3,
    float* __restrict__ out)
{
    __shared__ __align__(16) __half hxh[H_DIM];
    __shared__ __align__(16) __half hxl[H_DIM];
    __shared__ __align__(16) __half cxh[D_IN];
    __shared__ __align__(16) __half cxl[D_IN];
    __shared__ __align__(16) float gact[NCOL];
    __shared__ float w1[4][8][H_DIM];
    __shared__ float sb1[32];
    __shared__ float sW2[128];
    __shared__ float sb2[16];
    __shared__ float sW3[16];
    __shared__ float sb3[4];
    __shared__ float escale[4];

    const int b    = blockIdx.x;
    const int tid  = threadIdx.x;
    const int w    = tid >> 6;
    const int lane = tid & 63;

    for (int i = tid; i < 4 * 8 * H_DIM; i += 1024) {
        int p = i & 255;
        int base = i & ~255;
        int h = 4 * (p & 63) + (p >> 6);
        ((float*)w1)[i] = estW1[base + h];
    }
    if (tid < 32)  sb1[tid] = estb1[tid];
    if (tid < 128) sW2[tid] = estW2[tid];
    if (tid < 16)  { sb2[tid] = estb2[tid]; sW3[tid] = estW3[tid]; }
    if (tid < 4)   sb3[tid] = estb3[tid];
    if (tid < H_DIM) {
        hxh[tid] = __float2half(0.0f);
        hxl[tid] = __float2half(0.0f);
    }
    float c_reg = 0.0f, h_reg = 0.0f;
    const float b_j = biasc[tid];
    __syncthreads();

    const uint4* hh = (const uint4*)hxh;
    const uint4* hl = (const uint4*)hxl;
    const uint4* xh = (const uint4*)cxh;
    const uint4* xl = (const uint4*)cxl;

    for (int t = 0; t < T_STEPS; t++) {
        float aH = b_j, aL = 0.0f;
        if (tid < D_IN) {
            float xv = x[((size_t)t * BATCH + b) * D_IN + tid];
            __half hi = __float2half_rn(xv);
            cxh[tid] = hi;
            cxl[tid] = __float2half_rn(xv - __half2float(hi));
        }
        __syncthreads();
        #pragma unroll 4
        for (int m = 0; m < 32; m++) {
            uint4 wv = WX4[(m << 10) + tid];
            uint4 hv = xh[m], lv = xl[m];
            aH = dot2f(wv.x, hv.x, aH); aH = dot2f(wv.y, hv.y, aH);
            aH = dot2f(wv.z, hv.z, aH); aH = dot2f(wv.w, hv.w, aH);
            aL = dot2f(wv.x, lv.x, aL); aL = dot2f(wv.y, lv.y, aL);
            aL = dot2f(wv.z, lv.z, aL); aL = dot2f(wv.w, lv.w, aL);
        }
        #pragma unroll 4
        for (int m = 0; m < 32; m++) {
            uint4 wv = WH4[(m << 10) + tid];
            uint4 hv = hh[m], lv = hl[m];
            aH = dot2f(wv.x, hv.x, aH); aH = dot2f(wv.y, hv.y, aH);
            aH = dot2f(wv.z, hv.z, aH); aH = dot2f(wv.w, hv.w, aH);
            aL = dot2f(wv.x, lv.x, aL); aL = dot2f(wv.y, lv.y, aL);
            aL = dot2f(wv.z, lv.z, aL); aL = dot2f(wv.w, lv.w, aL);
        }
        float acc = aH + aL;

        float v = (tid >= 512 && tid < 768) ? tanhf_(acc) : sigmoidf_(acc);
        gact[tid] = v;
        __syncthreads();

        if (tid < 256) {
            float4 gv = ((const float4*)(gact + (w << 8)))[lane];
            float h1[8];
            #pragma unroll
            for (int j = 0; j < 8; j++) {
                const float* wr = &w1[w][j][0];
                float s = fmaf(gv.x, wr[lane],
                          fmaf(gv.y, wr[lane + 64],
                          fmaf(gv.z, wr[lane + 128], gv.w * wr[lane + 192])));
                #pragma unroll
                for (int m2 = 1; m2 < 64; m2 <<= 1) s += __shfl_xor(s, m2, 64);
                h1[j] = tanhf_(s + sb1[w * 8 + j]);
            }
            float h2[4];
            #pragma unroll
            for (int j = 0; j < 4; j++) {
                float s = sb2[w * 4 + j];
                #pragma unroll
                for (int q = 0; q < 8; q++) s = fmaf(h1[q], sW2[w * 32 + j * 8 + q], s);
                h2[j] = tanhf_(s);
            }
            float s3 = sb3[w];
            #pragma unroll
            for (int q = 0; q < 4; q++) s3 = fmaf(h2[q], sW3[w * 4 + q], s3);
            if (lane == 0) escale[w] = sigmoidf_(s3);
        }
        __syncthreads();

        if (tid < 256) {
            float f  = gact[tid]       * escale[0];
            float ii = gact[256 + tid] * escale[1];
            float gg = gact[512 + tid] * escale[2];
            float o  = gact[768 + tid] * escale[3];
            c_reg = fmaf(f, c_reg, ii * gg);
            h_reg = o * tanhf_(c_reg);
            __half hi = __float2half_rn(h_reg);
            hxh[tid] = hi;
            hxl[tid] = __float2half_rn(h_reg - __half2float(hi));
            out[((size_t)t * BATCH + b) * H_DIM + tid] = h_reg;
        }
        __syncthreads();
    }

    if (tid < 256) {
        const size_t stacked = (size_t)T_STEPS * BATCH * H_DIM;
        out[stacked + (size_t)b * H_DIM + tid] = h_reg;
        out[stacked + (size_t)BATCH * H_DIM + (size_t)b * H_DIM + tid] = c_reg;
    }
}

extern "C" void kernel_launch(void* const* d_in, const int* in_sizes, int n_in,
                              void* d_out, int out_size, void* d_ws, size_t ws_size,
                              hipStream_t stream) {
    const float* x     = (const float*)d_in[0];
    const float* Wf    = (const float*)d_in[1];
    const float* bf    = (const float*)d_in[2];
    const float* Wi    = (const float*)d_in[3];
    const float* bi    = (const float*)d_in[4];
    const float* Wg    = (const float*)d_in[5];
    const float* bg    = (const float*)d_in[6];
    const float* Wo    = (const float*)d_in[7];
    const float* bo    = (const float*)d_in[8];
    const float* estW1 = (const float*)d_in[9];
    const float* estb1 = (const float*)d_in[10];
    const float* estW2 = (const float*)d_in[11];
    const float* estb2 = (const float*)d_in[12];
    const float* estW3 = (const float*)d_in[13];
    const float* estb3 = (const float*)d_in[14];

    unsigned int* WX2 = (unsigned int*)d_ws;              // 512 KB (legacy, pregemm)
    uint4* WX4    = (uint4*)(WX2 + 128 * 1024);           // 512 KB
    uint4* WH4    = WX4 + 32 * 1024;                      // 512 KB
    float* biasc  = (float*)(WH4 + 32 * 1024);            // 4 KB
    int*   flags  = (int*)(biasc + NCOL);                 // 8192 ints = 32 KB
    float* partial= (float*)(flags + 8192);               // 512 KB
    unsigned int* hxbuf = (unsigned int*)(partial + (size_t)BATCH * NCOL); // 64 KB
    float* pre    = (float*)(hxbuf + (size_t)BATCH * 128);// [T*B][1024] fp32 = 512 MB

    const size_t fixed = (size_t)(512 + 512 + 512 + 4 + 32 + 512 + 64) * 1024;
    const size_t need  = fixed + (size_t)T_STEPS * BATCH * NCOL * 4;
    const int use_pre  = (ws_size >= need) ? 1 : 0;

    prep_kernel<<<128, 256, 0, stream>>>(Wf, Wi, Wg, Wo, bf, bi, bg, bo,
                                         WX2, WX4, WH4, biasc, flags);
    if (use_pre) {
        pregemm_kernel<<<(T_STEPS * BATCH) / 16, 256, 0, stream>>>(x, WX2, biasc, pre);
        qlstm_pair_kernel<<<2 * BATCH, 1024, 0, stream>>>(
            WH4, pre, partial, hxbuf, flags,
            estW1, estb1, estW2, estb2, estW3, estb3, (float*)d_out);
    } else {
        qlstm_fallback_kernel<<<BATCH, 1024, 0, stream>>>(
            x, WX4, WH4, biasc,
            estW1, estb1, estW2, estb2, estW3, estb3, (float*)d_out);
    }
}